// Round 3
// baseline (116.534 us; speedup 1.0000x reference)
//
#include <hip/hip_runtime.h>

// ---------------------------------------------------------------------------
// Single fused kernel. Every block redundantly rebuilds the 392-float
// coefficient table in LDS (~0.5 us, overlapped across blocks), then each
// thread processes 8 elements:
//   preact_l = bias_l + T_l . (1,cos x0,sin x0) (x) (1,cos x1,sin x1)
//   out = W2^T relu(preact) + b2
// x[:,2] is provably dead (global phase).
//
// R2 post-mortem: __launch_bounds__(256,4) + xa prefetch across the table
// build forced a 64-VGPR allocation -> scratch spill in the l-loop -> 103us
// with VALUBusy ~0.1%. Fix: no min-wave bound (grid caps occupancy at ~4
// waves/SIMD anyway) and load x AFTER the table build so the ~100-VGPR peak
// is only in the main loop.
// ---------------------------------------------------------------------------
__global__ __launch_bounds__(256) void q_fused(
    const float* __restrict__ x,
    const float* __restrict__ theta,
    const float* __restrict__ W1,   // (8,32)
    const float* __restrict__ b1,   // (32,)
    const float* __restrict__ W2,   // (32,2)
    const float* __restrict__ b2,   // (2,)
    float* __restrict__ out,
    int B)
{
    __shared__ float Ure[8][8];
    __shared__ float Uim[8][8];
    __shared__ float4 lt4[98];      // 392 floats

    const int lid  = threadIdx.x;
    const int t    = blockIdx.x * 256 + lid;
    const int base = t * 8;

    // ---- Phase 1: threads 0..7 build column `lid` of the fixed 8x8 unitary
    if (lid < 8) {
        float cr[8], ci[8];
        #pragma unroll
        for (int r = 0; r < 8; ++r) { cr[r] = (r == lid) ? 1.f : 0.f; ci[r] = 0.f; }

        auto rxmix = [&](int a, int b, float c_, float s_) {   // RX pair
            float ar = cr[a], ai = ci[a], br = cr[b], bi = ci[b];
            cr[a] = c_*ar + s_*bi;   ci[a] = c_*ai - s_*br;
            cr[b] = s_*ai + c_*br;   ci[b] = -s_*ar + c_*bi;
        };
        auto rymix = [&](int a, int b, float c_, float s_) {   // RY pair
            float ar = cr[a], ai = ci[a], br = cr[b], bi = ci[b];
            cr[a] = c_*ar - s_*br;   ci[a] = c_*ai - s_*bi;
            cr[b] = s_*ar + c_*br;   ci[b] = s_*ai + c_*bi;
        };
        auto zmul = [&](int r, float u, float v) {             // row *= (u+iv)
            float xr = cr[r], xi = ci[r];
            cr[r] = xr*u - xi*v;  ci[r] = xr*v + xi*u;
        };

        float c, s;
        // index = 4*i0 + 2*i1 + i2  (wire0 = MSB)
        __sincosf(theta[0]*0.5f, &s, &c);                       // RX wire0
        rxmix(0,4,c,s); rxmix(1,5,c,s); rxmix(2,6,c,s); rxmix(3,7,c,s);
        __sincosf(theta[1]*0.5f, &s, &c);                       // RY wire1
        rymix(0,2,c,s); rymix(1,3,c,s); rymix(4,6,c,s); rymix(5,7,c,s);
        __sincosf(theta[2]*0.5f, &s, &c);                       // RZ wire2
        #pragma unroll
        for (int r = 0; r < 8; ++r) zmul(r, c, (r & 1) ? s : -s);
        __sincosf(theta[3]*0.5f, &s, &c);                       // CRX 0->1
        rxmix(4,6,c,s); rxmix(5,7,c,s);
        __sincosf(theta[4]*0.5f, &s, &c);                       // RY wire2
        rymix(0,1,c,s); rymix(2,3,c,s); rymix(4,5,c,s); rymix(6,7,c,s);
        __sincosf(theta[5]*0.5f, &s, &c);                       // RX wire1
        rxmix(0,2,c,s); rxmix(1,3,c,s); rxmix(4,6,c,s); rxmix(5,7,c,s);
        __sincosf(theta[6]*0.5f, &s, &c);                       // CRX 1->2
        rxmix(2,3,c,s); rxmix(6,7,c,s);
        __sincosf(theta[7]*0.5f, &s, &c);                       // RZ wire0
        #pragma unroll
        for (int r = 0; r < 8; ++r) zmul(r, c, (r < 4) ? -s : s);

        #pragma unroll
        for (int r = 0; r < 8; ++r) { Ure[r][lid] = cr[r]; Uim[r][lid] = ci[r]; }
    }
    __syncthreads();

    // ---- Phase 2: threads 0..31 contract |U psi|^2 with W1/b1/W2 -> table
    if (lid < 32) {
        // W[:,m] = U[:,col(m)] * phase, col = {0,2,4,6}, phase = {1,1,-i,-i}
        float Wre[8][4], Wim[8][4];
        #pragma unroll
        for (int j = 0; j < 8; ++j) {
            Wre[j][0] =  Ure[j][0]; Wim[j][0] =  Uim[j][0];
            Wre[j][1] =  Ure[j][2]; Wim[j][1] =  Uim[j][2];
            Wre[j][2] =  Uim[j][4]; Wim[j][2] = -Ure[j][4];
            Wre[j][3] =  Uim[j][6]; Wim[j][3] = -Ure[j][6];
        }
        float Q[4][4];
        #pragma unroll
        for (int m = 0; m < 4; ++m)
            #pragma unroll
            for (int n = 0; n < 4; ++n) Q[m][n] = 0.f;
        #pragma unroll
        for (int j = 0; j < 8; ++j) {
            float w = W1[j*32 + lid];
            #pragma unroll
            for (int m = 0; m < 4; ++m)
                #pragma unroll
                for (int n = 0; n < 4; ++n)
                    Q[m][n] = fmaf(w, Wre[j][m]*Wre[j][n] + Wim[j][m]*Wim[j][n], Q[m][n]);
        }
        float R[3][3];
        R[0][0] = Q[0][0];
        R[0][1] = Q[0][1] + Q[1][0];
        R[0][2] = Q[1][1];
        R[1][0] = Q[0][2] + Q[2][0];
        R[1][1] = Q[0][3] + Q[1][2] + Q[2][1] + Q[3][0];
        R[1][2] = Q[1][3] + Q[3][1];
        R[2][0] = Q[2][2];
        R[2][1] = Q[2][3] + Q[3][2];
        R[2][2] = Q[3][3];
        float P[3][3];
        #pragma unroll
        for (int b = 0; b < 3; ++b) {
            P[0][b] = 0.5f*(R[0][b] + R[2][b]);
            P[1][b] = 0.5f*(R[0][b] - R[2][b]);
            P[2][b] = 0.5f*R[1][b];
        }
        float T[3][3];
        #pragma unroll
        for (int si = 0; si < 3; ++si) {
            T[si][0] = 0.5f*(P[si][0] + P[si][2]);
            T[si][1] = 0.5f*(P[si][0] - P[si][2]);
            T[si][2] = 0.5f*P[si][1];
        }
        float* row = ((float*)lt4) + lid*12;
        row[0] = T[0][1]; row[1] = T[0][2]; row[2] = T[1][0]; row[3] = T[2][0];
        row[4] = T[1][1]; row[5] = T[1][2]; row[6] = T[2][1]; row[7] = T[2][2];
        row[8] = b1[lid] + T[0][0];
        row[9]  = W2[lid*2+0];
        row[10] = W2[lid*2+1];
        row[11] = 0.f;
    }
    if (lid == 0) {
        float* f = (float*)lt4;
        f[384] = b2[0]; f[385] = b2[1]; f[386] = 0.f; f[387] = 0.f;
        f[388] = 0.f;   f[389] = 0.f;   f[390] = 0.f; f[391] = 0.f;
    }
    __syncthreads();

    const float* ltf = (const float*)lt4;
    const float b2a = ltf[384], b2b = ltf[385];

    if (base + 8 <= B) {
        // Load x only now — keeps the ~100-VGPR peak out of the precompute.
        float4 xa[6];
        const float4* X4 = (const float4*)x;
        #pragma unroll
        for (int i = 0; i < 6; ++i) xa[i] = X4[t*6 + i];

        const float* xf = (const float*)xa;
        float C0[8], S0[8], C1[8], S1[8], Pcc[8], Pcs[8], Psc[8], Pss[8];
        #pragma unroll
        for (int k = 0; k < 8; ++k) {
            __sincosf(xf[3*k+0], &S0[k], &C0[k]);
            __sincosf(xf[3*k+1], &S1[k], &C1[k]);
            Pcc[k] = C0[k]*C1[k]; Pcs[k] = C0[k]*S1[k];
            Psc[k] = S0[k]*C1[k]; Pss[k] = S0[k]*S1[k];
        }
        float acc0[8], acc1[8];
        #pragma unroll
        for (int k = 0; k < 8; ++k) { acc0[k] = b2a; acc1[k] = b2b; }

        #pragma unroll 1
        for (int l = 0; l < 32; ++l) {
            float4 cA = lt4[l*3+0];   // T01 T02 T10 T20
            float4 cB = lt4[l*3+1];   // T11 T12 T21 T22
            float4 cC = lt4[l*3+2];   // bias w2a w2b pad
            #pragma unroll
            for (int k = 0; k < 8; ++k) {
                float h = cC.x;
                h = fmaf(cA.x, C1[k],  h);
                h = fmaf(cA.y, S1[k],  h);
                h = fmaf(cA.z, C0[k],  h);
                h = fmaf(cA.w, S0[k],  h);
                h = fmaf(cB.x, Pcc[k], h);
                h = fmaf(cB.y, Pcs[k], h);
                h = fmaf(cB.z, Psc[k], h);
                h = fmaf(cB.w, Pss[k], h);
                h = fmaxf(h, 0.f);
                acc0[k] = fmaf(h, cC.y, acc0[k]);
                acc1[k] = fmaf(h, cC.z, acc1[k]);
            }
        }
        float4* O4 = (float4*)out;
        #pragma unroll
        for (int k = 0; k < 4; ++k)
            O4[t*4+k] = make_float4(acc0[2*k], acc1[2*k], acc0[2*k+1], acc1[2*k+1]);
    } else if (base < B) {
        // generic scalar tail (not hit for B = 2,000,000)
        for (int e = base; e < B; ++e) {
            float s0, c0, s1, c1;
            __sincosf(x[e*3+0], &s0, &c0);
            __sincosf(x[e*3+1], &s1, &c1);
            float pcc = c0*c1, pcs = c0*s1, psc = s0*c1, pss = s0*s1;
            float A0 = b2a, A1 = b2b;
            for (int l = 0; l < 32; ++l) {
                const float* row = ltf + l*12;
                float h = row[8];
                h = fmaf(row[0], c1,  h);
                h = fmaf(row[1], s1,  h);
                h = fmaf(row[2], c0,  h);
                h = fmaf(row[3], s0,  h);
                h = fmaf(row[4], pcc, h);
                h = fmaf(row[5], pcs, h);
                h = fmaf(row[6], psc, h);
                h = fmaf(row[7], pss, h);
                h = fmaxf(h, 0.f);
                A0 = fmaf(h, row[9],  A0);
                A1 = fmaf(h, row[10], A1);
            }
            out[e*2+0] = A0;
            out[e*2+1] = A1;
        }
    }
}

extern "C" void kernel_launch(void* const* d_in, const int* in_sizes, int n_in,
                              void* d_out, int out_size, void* d_ws, size_t ws_size,
                              hipStream_t stream) {
    const float* x     = (const float*)d_in[0];
    const float* theta = (const float*)d_in[1];
    const float* W1    = (const float*)d_in[2];
    const float* b1    = (const float*)d_in[3];
    const float* W2    = (const float*)d_in[4];
    const float* b2    = (const float*)d_in[5];
    float* out = (float*)d_out;

    const int B = in_sizes[0] / 3;
    const int nT = (B + 7) / 8;
    const int blocks = (nT + 255) / 256;
    q_fused<<<blocks, 256, 0, stream>>>(x, theta, W1, b1, W2, b2, out, B);
}

// Round 4
// 101.711 us; speedup vs baseline: 1.1457x; 1.1457x over previous
//
#include <hip/hip_runtime.h>

// ---------------------------------------------------------------------------
// Two kernels.
//  1) q_precompute (1 block, 64 thr): folds the whole theta-circuit + W1/b1/W2
//     into a 392-float table in d_ws. Row l (stride 12 floats, 48B):
//     [T01 T02 T10 T20 T11 T12 T21 T22 bias w2_l0 w2_l1 pad]; [384..385]=b2.
//  2) q_main: 8 elems/thread, out = W2^T relu(T_l . basis) + b2 with
//     basis = (1,cos x0,sin x0)(x)(1,cos x1,sin x1); x[:,2] dead (global phase).
//
// R3 post-mortem: per-block LDS table + broadcast ds_read_b128 made the l-loop
// LDS-return-bandwidth bound (8 waves/CU x 3 x 12cyc = 288 LDS-cyc per 176-cyc
// compute window) and VGPR=184 capped us at 2 waves/SIMD -> 46us, VALUBusy 35%.
// Fix: coefficients are wave-uniform -> scalar pipe. Uniform const-restrict
// float4 loads of the table compile to s_load_dwordx4; inner loop is pure
// v_fma with one SGPR operand. No LDS, no per-block build, no barriers.
// Trig via HW v_sin/v_cos (input in revolutions; |x|<6 rad is in range).
// ---------------------------------------------------------------------------

__global__ __launch_bounds__(64) void q_precompute(
    const float* __restrict__ theta,
    const float* __restrict__ W1,   // (8,32)
    const float* __restrict__ b1,   // (32,)
    const float* __restrict__ W2,   // (32,2)
    const float* __restrict__ b2,   // (2,)
    float* __restrict__ tab)
{
    __shared__ float Ure[8][8];
    __shared__ float Uim[8][8];
    const int t = threadIdx.x;

    if (t < 8) {
        float cr[8], ci[8];
        #pragma unroll
        for (int r = 0; r < 8; ++r) { cr[r] = (r == t) ? 1.f : 0.f; ci[r] = 0.f; }

        auto rxmix = [&](int a, int b, float c_, float s_) {   // RX pair
            float ar = cr[a], ai = ci[a], br = cr[b], bi = ci[b];
            cr[a] = c_*ar + s_*bi;   ci[a] = c_*ai - s_*br;
            cr[b] = s_*ai + c_*br;   ci[b] = -s_*ar + c_*bi;
        };
        auto rymix = [&](int a, int b, float c_, float s_) {   // RY pair
            float ar = cr[a], ai = ci[a], br = cr[b], bi = ci[b];
            cr[a] = c_*ar - s_*br;   ci[a] = c_*ai - s_*bi;
            cr[b] = s_*ar + c_*br;   ci[b] = s_*ai + c_*bi;
        };
        auto zmul = [&](int r, float u, float v) {             // row *= (u+iv)
            float xr = cr[r], xi = ci[r];
            cr[r] = xr*u - xi*v;  ci[r] = xr*v + xi*u;
        };

        float c, s;
        // index = 4*i0 + 2*i1 + i2  (wire0 = MSB)
        __sincosf(theta[0]*0.5f, &s, &c);                       // RX wire0
        rxmix(0,4,c,s); rxmix(1,5,c,s); rxmix(2,6,c,s); rxmix(3,7,c,s);
        __sincosf(theta[1]*0.5f, &s, &c);                       // RY wire1
        rymix(0,2,c,s); rymix(1,3,c,s); rymix(4,6,c,s); rymix(5,7,c,s);
        __sincosf(theta[2]*0.5f, &s, &c);                       // RZ wire2
        #pragma unroll
        for (int r = 0; r < 8; ++r) zmul(r, c, (r & 1) ? s : -s);
        __sincosf(theta[3]*0.5f, &s, &c);                       // CRX 0->1
        rxmix(4,6,c,s); rxmix(5,7,c,s);
        __sincosf(theta[4]*0.5f, &s, &c);                       // RY wire2
        rymix(0,1,c,s); rymix(2,3,c,s); rymix(4,5,c,s); rymix(6,7,c,s);
        __sincosf(theta[5]*0.5f, &s, &c);                       // RX wire1
        rxmix(0,2,c,s); rxmix(1,3,c,s); rxmix(4,6,c,s); rxmix(5,7,c,s);
        __sincosf(theta[6]*0.5f, &s, &c);                       // CRX 1->2
        rxmix(2,3,c,s); rxmix(6,7,c,s);
        __sincosf(theta[7]*0.5f, &s, &c);                       // RZ wire0
        #pragma unroll
        for (int r = 0; r < 8; ++r) zmul(r, c, (r < 4) ? -s : s);

        #pragma unroll
        for (int r = 0; r < 8; ++r) { Ure[r][t] = cr[r]; Uim[r][t] = ci[r]; }
    }
    __syncthreads();

    if (t < 32) {
        // W[:,m] = U[:,col(m)] * phase, col = {0,2,4,6}, phase = {1,1,-i,-i}
        float Wre[8][4], Wim[8][4];
        #pragma unroll
        for (int j = 0; j < 8; ++j) {
            Wre[j][0] =  Ure[j][0]; Wim[j][0] =  Uim[j][0];
            Wre[j][1] =  Ure[j][2]; Wim[j][1] =  Uim[j][2];
            Wre[j][2] =  Uim[j][4]; Wim[j][2] = -Ure[j][4];
            Wre[j][3] =  Uim[j][6]; Wim[j][3] = -Ure[j][6];
        }
        float Q[4][4];
        #pragma unroll
        for (int m = 0; m < 4; ++m)
            #pragma unroll
            for (int n = 0; n < 4; ++n) Q[m][n] = 0.f;
        #pragma unroll
        for (int j = 0; j < 8; ++j) {
            float w = W1[j*32 + t];
            #pragma unroll
            for (int m = 0; m < 4; ++m)
                #pragma unroll
                for (int n = 0; n < 4; ++n)
                    Q[m][n] = fmaf(w, Wre[j][m]*Wre[j][n] + Wim[j][m]*Wim[j][n], Q[m][n]);
        }
        float R[3][3];
        R[0][0] = Q[0][0];
        R[0][1] = Q[0][1] + Q[1][0];
        R[0][2] = Q[1][1];
        R[1][0] = Q[0][2] + Q[2][0];
        R[1][1] = Q[0][3] + Q[1][2] + Q[2][1] + Q[3][0];
        R[1][2] = Q[1][3] + Q[3][1];
        R[2][0] = Q[2][2];
        R[2][1] = Q[2][3] + Q[3][2];
        R[2][2] = Q[3][3];
        float P[3][3];
        #pragma unroll
        for (int b = 0; b < 3; ++b) {
            P[0][b] = 0.5f*(R[0][b] + R[2][b]);
            P[1][b] = 0.5f*(R[0][b] - R[2][b]);
            P[2][b] = 0.5f*R[1][b];
        }
        float T[3][3];
        #pragma unroll
        for (int si = 0; si < 3; ++si) {
            T[si][0] = 0.5f*(P[si][0] + P[si][2]);
            T[si][1] = 0.5f*(P[si][0] - P[si][2]);
            T[si][2] = 0.5f*P[si][1];
        }
        float* row = tab + t*12;
        row[0] = T[0][1]; row[1] = T[0][2]; row[2] = T[1][0]; row[3] = T[2][0];
        row[4] = T[1][1]; row[5] = T[1][2]; row[6] = T[2][1]; row[7] = T[2][2];
        row[8] = b1[t] + T[0][0];
        row[9]  = W2[t*2+0];
        row[10] = W2[t*2+1];
        row[11] = 0.f;
    }
    if (t == 0) { tab[384] = b2[0]; tab[385] = b2[1]; tab[386] = 0.f; tab[387] = 0.f; }
}

#define INV_2PI 0.15915494309189535f

__global__ __launch_bounds__(256) void q_main(
    const float* __restrict__ x,
    const float* __restrict__ tab,
    float* __restrict__ out,
    int B)
{
    const int t    = blockIdx.x * 256 + threadIdx.x;
    const int base = t * 8;
    if (base >= B) return;

    // b2 (uniform -> sgpr)
    const float b2a = tab[384], b2b = tab[385];

    if (base + 8 <= B) {
        // 96 B/thread of x, fully covered by 6 dwordx4 per thread.
        float4 xa[6];
        const float4* X4 = (const float4*)x;
        #pragma unroll
        for (int i = 0; i < 6; ++i) xa[i] = X4[t*6 + i];

        const float* xf = (const float*)xa;
        float C0[8], S0[8], C1[8], S1[8], Pcc[8], Pcs[8], Psc[8], Pss[8];
        #pragma unroll
        for (int k = 0; k < 8; ++k) {
            // HW sin/cos take revolutions; |x| < ~6 rad is well inside range.
            float r0 = xf[3*k+0] * INV_2PI;
            float r1 = xf[3*k+1] * INV_2PI;
            S0[k] = __builtin_amdgcn_sinf(r0);
            C0[k] = __builtin_amdgcn_cosf(r0);
            S1[k] = __builtin_amdgcn_sinf(r1);
            C1[k] = __builtin_amdgcn_cosf(r1);
            Pcc[k] = C0[k]*C1[k]; Pcs[k] = C0[k]*S1[k];
            Psc[k] = S0[k]*C1[k]; Pss[k] = S0[k]*S1[k];
        }
        float acc0[8], acc1[8];
        #pragma unroll
        for (int k = 0; k < 8; ++k) { acc0[k] = b2a; acc1[k] = b2b; }

        const float4* T4 = (const float4*)tab;   // uniform -> s_load
        #pragma unroll 2
        for (int l = 0; l < 32; ++l) {
            float4 cA = T4[l*3+0];   // T01 T02 T10 T20   (s_load_dwordx4)
            float4 cB = T4[l*3+1];   // T11 T12 T21 T22
            float4 cC = T4[l*3+2];   // bias w2a w2b pad
            #pragma unroll
            for (int k = 0; k < 8; ++k) {
                float h = cC.x;
                h = fmaf(cA.x, C1[k],  h);
                h = fmaf(cA.y, S1[k],  h);
                h = fmaf(cA.z, C0[k],  h);
                h = fmaf(cA.w, S0[k],  h);
                h = fmaf(cB.x, Pcc[k], h);
                h = fmaf(cB.y, Pcs[k], h);
                h = fmaf(cB.z, Psc[k], h);
                h = fmaf(cB.w, Pss[k], h);
                h = fmaxf(h, 0.f);
                acc0[k] = fmaf(h, cC.y, acc0[k]);
                acc1[k] = fmaf(h, cC.z, acc1[k]);
            }
        }
        float4* O4 = (float4*)out;
        #pragma unroll
        for (int k = 0; k < 4; ++k)
            O4[t*4+k] = make_float4(acc0[2*k], acc1[2*k], acc0[2*k+1], acc1[2*k+1]);
    } else {
        // generic scalar tail (not hit for B = 2,000,000)
        for (int e = base; e < B; ++e) {
            float s0, c0, s1, c1;
            float r0 = x[e*3+0] * INV_2PI;
            float r1 = x[e*3+1] * INV_2PI;
            s0 = __builtin_amdgcn_sinf(r0); c0 = __builtin_amdgcn_cosf(r0);
            s1 = __builtin_amdgcn_sinf(r1); c1 = __builtin_amdgcn_cosf(r1);
            float pcc = c0*c1, pcs = c0*s1, psc = s0*c1, pss = s0*s1;
            float A0 = b2a, A1 = b2b;
            for (int l = 0; l < 32; ++l) {
                const float* row = tab + l*12;
                float h = row[8];
                h = fmaf(row[0], c1,  h);
                h = fmaf(row[1], s1,  h);
                h = fmaf(row[2], c0,  h);
                h = fmaf(row[3], s0,  h);
                h = fmaf(row[4], pcc, h);
                h = fmaf(row[5], pcs, h);
                h = fmaf(row[6], psc, h);
                h = fmaf(row[7], pss, h);
                h = fmaxf(h, 0.f);
                A0 = fmaf(h, row[9],  A0);
                A1 = fmaf(h, row[10], A1);
            }
            out[e*2+0] = A0;
            out[e*2+1] = A1;
        }
    }
}

extern "C" void kernel_launch(void* const* d_in, const int* in_sizes, int n_in,
                              void* d_out, int out_size, void* d_ws, size_t ws_size,
                              hipStream_t stream) {
    const float* x     = (const float*)d_in[0];
    const float* theta = (const float*)d_in[1];
    const float* W1    = (const float*)d_in[2];
    const float* b1    = (const float*)d_in[3];
    const float* W2    = (const float*)d_in[4];
    const float* b2    = (const float*)d_in[5];
    float* out = (float*)d_out;
    float* tab = (float*)d_ws;

    const int B = in_sizes[0] / 3;

    q_precompute<<<1, 64, 0, stream>>>(theta, W1, b1, W2, b2, tab);

    const int nT = (B + 7) / 8;
    const int blocks = (nT + 255) / 256;
    q_main<<<blocks, 256, 0, stream>>>(x, tab, out, B);
}

// Round 5
// 97.787 us; speedup vs baseline: 1.1917x; 1.0401x over previous
//
#include <hip/hip_runtime.h>

// ---------------------------------------------------------------------------
// Two kernels.
//  1) q_precompute (1 block, 64 thr): folds the whole theta-circuit + W1/b1/W2
//     into a 392-float table in d_ws. Row l (stride 12 floats, 48B):
//     [T01 T02 T10 T20 T11 T12 T21 T22 bias w2_l0 w2_l1 pad]; [384..385]=b2.
//  2) q_main: out = W2^T relu(T_l . basis) + b2,
//     basis = (1,cos x0,sin x0)(x)(1,cos x1,sin x1); x[:,2] dead (global phase).
//
// R4 post-mortem: contiguous-per-thread element mapping made every global
// access 96B/64B lane-strided -> ~4-6x L1 line-request amplification ->
// VMEM-bound at ~32us (3x the ~10us VALU floor). Fix:
//  - element k of thread t = blockBase + k*256 + t  -> x loads are 2 coalesced
//    dwords (x2 bytes never loaded), out stores one coalesced dwordx2/elem.
//  - 4 elems/thread packed as 2 x float2, l-loop in v_pk_fma_f32 (halves
//    instruction issue; table stays in SGPRs via uniform s_load_dwordx4).
// ---------------------------------------------------------------------------

typedef float f32x2 __attribute__((ext_vector_type(2)));

static __device__ __forceinline__ f32x2 pk_fma(f32x2 a, f32x2 b, f32x2 c) {
    return __builtin_elementwise_fma(a, b, c);
}
static __device__ __forceinline__ f32x2 splat2(float v) {
    f32x2 r; r.x = v; r.y = v; return r;
}

__global__ __launch_bounds__(64) void q_precompute(
    const float* __restrict__ theta,
    const float* __restrict__ W1,   // (8,32)
    const float* __restrict__ b1,   // (32,)
    const float* __restrict__ W2,   // (32,2)
    const float* __restrict__ b2,   // (2,)
    float* __restrict__ tab)
{
    __shared__ float Ure[8][8];
    __shared__ float Uim[8][8];
    const int t = threadIdx.x;

    if (t < 8) {
        float cr[8], ci[8];
        #pragma unroll
        for (int r = 0; r < 8; ++r) { cr[r] = (r == t) ? 1.f : 0.f; ci[r] = 0.f; }

        auto rxmix = [&](int a, int b, float c_, float s_) {   // RX pair
            float ar = cr[a], ai = ci[a], br = cr[b], bi = ci[b];
            cr[a] = c_*ar + s_*bi;   ci[a] = c_*ai - s_*br;
            cr[b] = s_*ai + c_*br;   ci[b] = -s_*ar + c_*bi;
        };
        auto rymix = [&](int a, int b, float c_, float s_) {   // RY pair
            float ar = cr[a], ai = ci[a], br = cr[b], bi = ci[b];
            cr[a] = c_*ar - s_*br;   ci[a] = c_*ai - s_*bi;
            cr[b] = s_*ar + c_*br;   ci[b] = s_*ai + c_*bi;
        };
        auto zmul = [&](int r, float u, float v) {             // row *= (u+iv)
            float xr = cr[r], xi = ci[r];
            cr[r] = xr*u - xi*v;  ci[r] = xr*v + xi*u;
        };

        float c, s;
        // index = 4*i0 + 2*i1 + i2  (wire0 = MSB)
        __sincosf(theta[0]*0.5f, &s, &c);                       // RX wire0
        rxmix(0,4,c,s); rxmix(1,5,c,s); rxmix(2,6,c,s); rxmix(3,7,c,s);
        __sincosf(theta[1]*0.5f, &s, &c);                       // RY wire1
        rymix(0,2,c,s); rymix(1,3,c,s); rymix(4,6,c,s); rymix(5,7,c,s);
        __sincosf(theta[2]*0.5f, &s, &c);                       // RZ wire2
        #pragma unroll
        for (int r = 0; r < 8; ++r) zmul(r, c, (r & 1) ? s : -s);
        __sincosf(theta[3]*0.5f, &s, &c);                       // CRX 0->1
        rxmix(4,6,c,s); rxmix(5,7,c,s);
        __sincosf(theta[4]*0.5f, &s, &c);                       // RY wire2
        rymix(0,1,c,s); rymix(2,3,c,s); rymix(4,5,c,s); rymix(6,7,c,s);
        __sincosf(theta[5]*0.5f, &s, &c);                       // RX wire1
        rxmix(0,2,c,s); rxmix(1,3,c,s); rxmix(4,6,c,s); rxmix(5,7,c,s);
        __sincosf(theta[6]*0.5f, &s, &c);                       // CRX 1->2
        rxmix(2,3,c,s); rxmix(6,7,c,s);
        __sincosf(theta[7]*0.5f, &s, &c);                       // RZ wire0
        #pragma unroll
        for (int r = 0; r < 8; ++r) zmul(r, c, (r < 4) ? -s : s);

        #pragma unroll
        for (int r = 0; r < 8; ++r) { Ure[r][t] = cr[r]; Uim[r][t] = ci[r]; }
    }
    __syncthreads();

    if (t < 32) {
        // W[:,m] = U[:,col(m)] * phase, col = {0,2,4,6}, phase = {1,1,-i,-i}
        float Wre[8][4], Wim[8][4];
        #pragma unroll
        for (int j = 0; j < 8; ++j) {
            Wre[j][0] =  Ure[j][0]; Wim[j][0] =  Uim[j][0];
            Wre[j][1] =  Ure[j][2]; Wim[j][1] =  Uim[j][2];
            Wre[j][2] =  Uim[j][4]; Wim[j][2] = -Ure[j][4];
            Wre[j][3] =  Uim[j][6]; Wim[j][3] = -Ure[j][6];
        }
        float Q[4][4];
        #pragma unroll
        for (int m = 0; m < 4; ++m)
            #pragma unroll
            for (int n = 0; n < 4; ++n) Q[m][n] = 0.f;
        #pragma unroll
        for (int j = 0; j < 8; ++j) {
            float w = W1[j*32 + t];
            #pragma unroll
            for (int m = 0; m < 4; ++m)
                #pragma unroll
                for (int n = 0; n < 4; ++n)
                    Q[m][n] = fmaf(w, Wre[j][m]*Wre[j][n] + Wim[j][m]*Wim[j][n], Q[m][n]);
        }
        float R[3][3];
        R[0][0] = Q[0][0];
        R[0][1] = Q[0][1] + Q[1][0];
        R[0][2] = Q[1][1];
        R[1][0] = Q[0][2] + Q[2][0];
        R[1][1] = Q[0][3] + Q[1][2] + Q[2][1] + Q[3][0];
        R[1][2] = Q[1][3] + Q[3][1];
        R[2][0] = Q[2][2];
        R[2][1] = Q[2][3] + Q[3][2];
        R[2][2] = Q[3][3];
        float P[3][3];
        #pragma unroll
        for (int b = 0; b < 3; ++b) {
            P[0][b] = 0.5f*(R[0][b] + R[2][b]);
            P[1][b] = 0.5f*(R[0][b] - R[2][b]);
            P[2][b] = 0.5f*R[1][b];
        }
        float T[3][3];
        #pragma unroll
        for (int si = 0; si < 3; ++si) {
            T[si][0] = 0.5f*(P[si][0] + P[si][2]);
            T[si][1] = 0.5f*(P[si][0] - P[si][2]);
            T[si][2] = 0.5f*P[si][1];
        }
        float* row = tab + t*12;
        row[0] = T[0][1]; row[1] = T[0][2]; row[2] = T[1][0]; row[3] = T[2][0];
        row[4] = T[1][1]; row[5] = T[1][2]; row[6] = T[2][1]; row[7] = T[2][2];
        row[8] = b1[t] + T[0][0];
        row[9]  = W2[t*2+0];
        row[10] = W2[t*2+1];
        row[11] = 0.f;
    }
    if (t == 0) { tab[384] = b2[0]; tab[385] = b2[1]; tab[386] = 0.f; tab[387] = 0.f; }
}

#define INV_2PI 0.15915494309189535f

__global__ __launch_bounds__(256) void q_main(
    const float* __restrict__ x,
    const float* __restrict__ tab,
    float* __restrict__ out,
    int B)
{
    const int lid = threadIdx.x;
    const int bb  = blockIdx.x * 1024;          // 4 elems/thread * 256 thr
    const int e0  = bb + lid;                   // element for slot k: e0 + k*256

    const float b2a = tab[384], b2b = tab[385]; // uniform -> sgpr
    const float4* T4 = (const float4*)tab;      // uniform -> s_load_dwordx4

    if (bb + 1024 <= B) {
        // Coalesced loads: lane stride 12 B; x[:,2] bytes never requested.
        float xs0[4], xs1[4];
        #pragma unroll
        for (int k = 0; k < 4; ++k) {
            const int e = e0 + k*256;
            xs0[k] = x[e*3 + 0];
            xs1[k] = x[e*3 + 1];
        }

        // Trig (HW sin/cos in revolutions; |x|<~6 rad is in range), packed
        // into 2 x float2 groups: group g holds elements k=2g, 2g+1.
        f32x2 c0v[2], s0v[2], c1v[2], s1v[2], pcc[2], pcs[2], psc[2], pss[2];
        #pragma unroll
        for (int g = 0; g < 2; ++g) {
            #pragma unroll
            for (int j = 0; j < 2; ++j) {
                const int k = 2*g + j;
                const float r0 = xs0[k] * INV_2PI;
                const float r1 = xs1[k] * INV_2PI;
                s0v[g][j] = __builtin_amdgcn_sinf(r0);
                c0v[g][j] = __builtin_amdgcn_cosf(r0);
                s1v[g][j] = __builtin_amdgcn_sinf(r1);
                c1v[g][j] = __builtin_amdgcn_cosf(r1);
            }
            pcc[g] = c0v[g]*c1v[g]; pcs[g] = c0v[g]*s1v[g];
            psc[g] = s0v[g]*c1v[g]; pss[g] = s0v[g]*s1v[g];
        }

        f32x2 a0v[2], a1v[2];
        #pragma unroll
        for (int g = 0; g < 2; ++g) { a0v[g] = splat2(b2a); a1v[g] = splat2(b2b); }

        #pragma unroll 2
        for (int l = 0; l < 32; ++l) {
            const float4 cA = T4[l*3+0];   // T01 T02 T10 T20
            const float4 cB = T4[l*3+1];   // T11 T12 T21 T22
            const float4 cC = T4[l*3+2];   // bias w2a w2b pad
            #pragma unroll
            for (int g = 0; g < 2; ++g) {
                f32x2 h = pk_fma(splat2(cA.x), c1v[g], splat2(cC.x));
                h = pk_fma(splat2(cA.y), s1v[g], h);
                h = pk_fma(splat2(cA.z), c0v[g], h);
                h = pk_fma(splat2(cA.w), s0v[g], h);
                h = pk_fma(splat2(cB.x), pcc[g], h);
                h = pk_fma(splat2(cB.y), pcs[g], h);
                h = pk_fma(splat2(cB.z), psc[g], h);
                h = pk_fma(splat2(cB.w), pss[g], h);
                h = __builtin_elementwise_max(h, splat2(0.f));
                a0v[g] = pk_fma(h, splat2(cC.y), a0v[g]);
                a1v[g] = pk_fma(h, splat2(cC.z), a1v[g]);
            }
        }

        // Coalesced stores: one dwordx2 per element, lane stride 8 B.
        f32x2* O2 = (f32x2*)out;
        #pragma unroll
        for (int k = 0; k < 4; ++k) {
            const int e = e0 + k*256;
            f32x2 o; o.x = a0v[k>>1][k&1]; o.y = a1v[k>>1][k&1];
            O2[e] = o;
        }
    } else {
        // Tail block: per-element predicated scalar path.
        for (int k = 0; k < 4; ++k) {
            const int e = e0 + k*256;
            if (e >= B) continue;
            const float r0 = x[e*3+0] * INV_2PI;
            const float r1 = x[e*3+1] * INV_2PI;
            const float s0 = __builtin_amdgcn_sinf(r0), c0 = __builtin_amdgcn_cosf(r0);
            const float s1 = __builtin_amdgcn_sinf(r1), c1 = __builtin_amdgcn_cosf(r1);
            const float pc = c0*c1, ps = c0*s1, sc = s0*c1, ss = s0*s1;
            float A0 = b2a, A1 = b2b;
            for (int l = 0; l < 32; ++l) {
                const float4 cA = T4[l*3+0];
                const float4 cB = T4[l*3+1];
                const float4 cC = T4[l*3+2];
                float h = cC.x;
                h = fmaf(cA.x, c1, h);
                h = fmaf(cA.y, s1, h);
                h = fmaf(cA.z, c0, h);
                h = fmaf(cA.w, s0, h);
                h = fmaf(cB.x, pc, h);
                h = fmaf(cB.y, ps, h);
                h = fmaf(cB.z, sc, h);
                h = fmaf(cB.w, ss, h);
                h = fmaxf(h, 0.f);
                A0 = fmaf(h, cC.y, A0);
                A1 = fmaf(h, cC.z, A1);
            }
            out[e*2+0] = A0;
            out[e*2+1] = A1;
        }
    }
}

extern "C" void kernel_launch(void* const* d_in, const int* in_sizes, int n_in,
                              void* d_out, int out_size, void* d_ws, size_t ws_size,
                              hipStream_t stream) {
    const float* x     = (const float*)d_in[0];
    const float* theta = (const float*)d_in[1];
    const float* W1    = (const float*)d_in[2];
    const float* b1    = (const float*)d_in[3];
    const float* W2    = (const float*)d_in[4];
    const float* b2    = (const float*)d_in[5];
    float* out = (float*)d_out;
    float* tab = (float*)d_ws;

    const int B = in_sizes[0] / 3;

    q_precompute<<<1, 64, 0, stream>>>(theta, W1, b1, W2, b2, tab);

    const int blocks = (B + 1023) / 1024;       // 4 elems/thread * 256 thr
    q_main<<<blocks, 256, 0, stream>>>(x, tab, out, B);
}

// Round 6
// 97.397 us; speedup vs baseline: 1.1965x; 1.0040x over previous
//
#include <hip/hip_runtime.h>

// ---------------------------------------------------------------------------
// Two kernels.
//  1) q_precompute (1 block, 64 thr = 1 wave): folds the theta-circuit +
//     W1/b1/W2 into a 392-float table in d_ws. Row l (stride 12 floats):
//     [T01 T02 T10 T20 T11 T12 T21 T22 bias w2_l0 w2_l1 pad]; [384..385]=b2.
//  2) q_main: out = W2^T relu(T_l . basis) + b2,
//     basis = (1,cos x0,sin x0)(x)(1,cos x1,sin x1); x[:,2] dead (global phase).
//
// R5 post-mortem: coalescing fix gave only -4us -> the limiter is coefficient
// -load latency in the l-loop (96 uniform loads per thread-loop, shallow
// 2-iter lookahead) + precompute serialization (ocml sincos). R6:
//  - 8 elems/thread (strided, coalesced) as 4 f32x2 pk groups: halves table
//    loads per element, 176-cyc compute per l-iter.
//  - #pragma unroll 4: 12 coefficient loads in flight.
//  - HW v_sin/v_cos in precompute (|theta|<~6 rad: in range, no reduction).
// ---------------------------------------------------------------------------

typedef float f32x2 __attribute__((ext_vector_type(2)));

static __device__ __forceinline__ f32x2 pk_fma(f32x2 a, f32x2 b, f32x2 c) {
    return __builtin_elementwise_fma(a, b, c);
}
static __device__ __forceinline__ f32x2 splat2(float v) {
    f32x2 r; r.x = v; r.y = v; return r;
}

#define INV_2PI 0.15915494309189535f

__global__ __launch_bounds__(64) void q_precompute(
    const float* __restrict__ theta,
    const float* __restrict__ W1,   // (8,32)
    const float* __restrict__ b1,   // (32,)
    const float* __restrict__ W2,   // (32,2)
    const float* __restrict__ b2,   // (2,)
    float* __restrict__ tab)
{
    __shared__ float Ure[8][8];
    __shared__ float Uim[8][8];
    const int t = threadIdx.x;

    if (t < 8) {
        float cr[8], ci[8];
        #pragma unroll
        for (int r = 0; r < 8; ++r) { cr[r] = (r == t) ? 1.f : 0.f; ci[r] = 0.f; }

        auto rxmix = [&](int a, int b, float c_, float s_) {   // RX pair
            float ar = cr[a], ai = ci[a], br = cr[b], bi = ci[b];
            cr[a] = c_*ar + s_*bi;   ci[a] = c_*ai - s_*br;
            cr[b] = s_*ai + c_*br;   ci[b] = -s_*ar + c_*bi;
        };
        auto rymix = [&](int a, int b, float c_, float s_) {   // RY pair
            float ar = cr[a], ai = ci[a], br = cr[b], bi = ci[b];
            cr[a] = c_*ar - s_*br;   ci[a] = c_*ai - s_*bi;
            cr[b] = s_*ar + c_*br;   ci[b] = s_*ai + c_*bi;
        };
        auto zmul = [&](int r, float u, float v) {             // row *= (u+iv)
            float xr = cr[r], xi = ci[r];
            cr[r] = xr*u - xi*v;  ci[r] = xr*v + xi*u;
        };
        // HW trig: revolutions; theta ~ N(0,1) so theta/2 is far inside range.
        auto hsin = [&](float a) { return __builtin_amdgcn_sinf(a * (0.5f*INV_2PI)); };
        auto hcos = [&](float a) { return __builtin_amdgcn_cosf(a * (0.5f*INV_2PI)); };

        float c, s;
        // index = 4*i0 + 2*i1 + i2  (wire0 = MSB)
        c = hcos(theta[0]); s = hsin(theta[0]);                 // RX wire0
        rxmix(0,4,c,s); rxmix(1,5,c,s); rxmix(2,6,c,s); rxmix(3,7,c,s);
        c = hcos(theta[1]); s = hsin(theta[1]);                 // RY wire1
        rymix(0,2,c,s); rymix(1,3,c,s); rymix(4,6,c,s); rymix(5,7,c,s);
        c = hcos(theta[2]); s = hsin(theta[2]);                 // RZ wire2
        #pragma unroll
        for (int r = 0; r < 8; ++r) zmul(r, c, (r & 1) ? s : -s);
        c = hcos(theta[3]); s = hsin(theta[3]);                 // CRX 0->1
        rxmix(4,6,c,s); rxmix(5,7,c,s);
        c = hcos(theta[4]); s = hsin(theta[4]);                 // RY wire2
        rymix(0,1,c,s); rymix(2,3,c,s); rymix(4,5,c,s); rymix(6,7,c,s);
        c = hcos(theta[5]); s = hsin(theta[5]);                 // RX wire1
        rxmix(0,2,c,s); rxmix(1,3,c,s); rxmix(4,6,c,s); rxmix(5,7,c,s);
        c = hcos(theta[6]); s = hsin(theta[6]);                 // CRX 1->2
        rxmix(2,3,c,s); rxmix(6,7,c,s);
        c = hcos(theta[7]); s = hsin(theta[7]);                 // RZ wire0
        #pragma unroll
        for (int r = 0; r < 8; ++r) zmul(r, c, (r < 4) ? -s : s);

        #pragma unroll
        for (int r = 0; r < 8; ++r) { Ure[r][t] = cr[r]; Uim[r][t] = ci[r]; }
    }
    __syncthreads();   // single wave: cheap

    if (t < 32) {
        // W[:,m] = U[:,col(m)] * phase, col = {0,2,4,6}, phase = {1,1,-i,-i}
        float Wre[8][4], Wim[8][4];
        #pragma unroll
        for (int j = 0; j < 8; ++j) {
            Wre[j][0] =  Ure[j][0]; Wim[j][0] =  Uim[j][0];
            Wre[j][1] =  Ure[j][2]; Wim[j][1] =  Uim[j][2];
            Wre[j][2] =  Uim[j][4]; Wim[j][2] = -Ure[j][4];
            Wre[j][3] =  Uim[j][6]; Wim[j][3] = -Ure[j][6];
        }
        float Q[4][4];
        #pragma unroll
        for (int m = 0; m < 4; ++m)
            #pragma unroll
            for (int n = 0; n < 4; ++n) Q[m][n] = 0.f;
        #pragma unroll
        for (int j = 0; j < 8; ++j) {
            float w = W1[j*32 + t];
            #pragma unroll
            for (int m = 0; m < 4; ++m)
                #pragma unroll
                for (int n = 0; n < 4; ++n)
                    Q[m][n] = fmaf(w, Wre[j][m]*Wre[j][n] + Wim[j][m]*Wim[j][n], Q[m][n]);
        }
        float R[3][3];
        R[0][0] = Q[0][0];
        R[0][1] = Q[0][1] + Q[1][0];
        R[0][2] = Q[1][1];
        R[1][0] = Q[0][2] + Q[2][0];
        R[1][1] = Q[0][3] + Q[1][2] + Q[2][1] + Q[3][0];
        R[1][2] = Q[1][3] + Q[3][1];
        R[2][0] = Q[2][2];
        R[2][1] = Q[2][3] + Q[3][2];
        R[2][2] = Q[3][3];
        float P[3][3];
        #pragma unroll
        for (int b = 0; b < 3; ++b) {
            P[0][b] = 0.5f*(R[0][b] + R[2][b]);
            P[1][b] = 0.5f*(R[0][b] - R[2][b]);
            P[2][b] = 0.5f*R[1][b];
        }
        float T[3][3];
        #pragma unroll
        for (int si = 0; si < 3; ++si) {
            T[si][0] = 0.5f*(P[si][0] + P[si][2]);
            T[si][1] = 0.5f*(P[si][0] - P[si][2]);
            T[si][2] = 0.5f*P[si][1];
        }
        float* row = tab + t*12;
        row[0] = T[0][1]; row[1] = T[0][2]; row[2] = T[1][0]; row[3] = T[2][0];
        row[4] = T[1][1]; row[5] = T[1][2]; row[6] = T[2][1]; row[7] = T[2][2];
        row[8] = b1[t] + T[0][0];
        row[9]  = W2[t*2+0];
        row[10] = W2[t*2+1];
        row[11] = 0.f;
    }
    if (t == 0) { tab[384] = b2[0]; tab[385] = b2[1]; tab[386] = 0.f; tab[387] = 0.f; }
}

__global__ __launch_bounds__(256) void q_main(
    const float* __restrict__ x,
    const float* __restrict__ tab,
    float* __restrict__ out,
    int B)
{
    const int lid = threadIdx.x;
    const int bb  = blockIdx.x * 2048;          // 8 elems/thread * 256 thr
    const int e0  = bb + lid;                   // element slot k: e0 + k*256

    const float b2a = tab[384], b2b = tab[385]; // uniform -> sgpr
    const float4* T4 = (const float4*)tab;      // uniform -> s_load_dwordx4

    if (bb + 2048 <= B) {
        // Coalesced: lane stride 12 B; x[:,2] bytes never requested.
        float xs0[8], xs1[8];
        #pragma unroll
        for (int k = 0; k < 8; ++k) {
            const int e = e0 + k*256;
            xs0[k] = x[e*3 + 0];
            xs1[k] = x[e*3 + 1];
        }

        // HW trig (revolutions; |x|<~6 rad in range). Group g = elems 2g,2g+1.
        f32x2 c0v[4], s0v[4], c1v[4], s1v[4], pcc[4], pcs[4], psc[4], pss[4];
        #pragma unroll
        for (int g = 0; g < 4; ++g) {
            #pragma unroll
            for (int j = 0; j < 2; ++j) {
                const int k = 2*g + j;
                const float r0 = xs0[k] * INV_2PI;
                const float r1 = xs1[k] * INV_2PI;
                s0v[g][j] = __builtin_amdgcn_sinf(r0);
                c0v[g][j] = __builtin_amdgcn_cosf(r0);
                s1v[g][j] = __builtin_amdgcn_sinf(r1);
                c1v[g][j] = __builtin_amdgcn_cosf(r1);
            }
            pcc[g] = c0v[g]*c1v[g]; pcs[g] = c0v[g]*s1v[g];
            psc[g] = s0v[g]*c1v[g]; pss[g] = s0v[g]*s1v[g];
        }

        f32x2 a0v[4], a1v[4];
        #pragma unroll
        for (int g = 0; g < 4; ++g) { a0v[g] = splat2(b2a); a1v[g] = splat2(b2b); }

        #pragma unroll 4
        for (int l = 0; l < 32; ++l) {
            const float4 cA = T4[l*3+0];   // T01 T02 T10 T20
            const float4 cB = T4[l*3+1];   // T11 T12 T21 T22
            const float4 cC = T4[l*3+2];   // bias w2a w2b pad
            #pragma unroll
            for (int g = 0; g < 4; ++g) {
                f32x2 h = pk_fma(splat2(cA.x), c1v[g], splat2(cC.x));
                h = pk_fma(splat2(cA.y), s1v[g], h);
                h = pk_fma(splat2(cA.z), c0v[g], h);
                h = pk_fma(splat2(cA.w), s0v[g], h);
                h = pk_fma(splat2(cB.x), pcc[g], h);
                h = pk_fma(splat2(cB.y), pcs[g], h);
                h = pk_fma(splat2(cB.z), psc[g], h);
                h = pk_fma(splat2(cB.w), pss[g], h);
                h = __builtin_elementwise_max(h, splat2(0.f));
                a0v[g] = pk_fma(h, splat2(cC.y), a0v[g]);
                a1v[g] = pk_fma(h, splat2(cC.z), a1v[g]);
            }
        }

        // Coalesced stores: one dwordx2 per element, lane stride 8 B.
        f32x2* O2 = (f32x2*)out;
        #pragma unroll
        for (int k = 0; k < 8; ++k) {
            const int e = e0 + k*256;
            f32x2 o; o.x = a0v[k>>1][k&1]; o.y = a1v[k>>1][k&1];
            O2[e] = o;
        }
    } else {
        // Tail block: per-element predicated scalar path.
        for (int k = 0; k < 8; ++k) {
            const int e = e0 + k*256;
            if (e >= B) continue;
            const float r0 = x[e*3+0] * INV_2PI;
            const float r1 = x[e*3+1] * INV_2PI;
            const float s0 = __builtin_amdgcn_sinf(r0), c0 = __builtin_amdgcn_cosf(r0);
            const float s1 = __builtin_amdgcn_sinf(r1), c1 = __builtin_amdgcn_cosf(r1);
            const float pc = c0*c1, ps = c0*s1, sc = s0*c1, ss = s0*s1;
            float A0 = b2a, A1 = b2b;
            for (int l = 0; l < 32; ++l) {
                const float4 cA = T4[l*3+0];
                const float4 cB = T4[l*3+1];
                const float4 cC = T4[l*3+2];
                float h = cC.x;
                h = fmaf(cA.x, c1, h);
                h = fmaf(cA.y, s1, h);
                h = fmaf(cA.z, c0, h);
                h = fmaf(cA.w, s0, h);
                h = fmaf(cB.x, pc, h);
                h = fmaf(cB.y, ps, h);
                h = fmaf(cB.z, sc, h);
                h = fmaf(cB.w, ss, h);
                h = fmaxf(h, 0.f);
                A0 = fmaf(h, cC.y, A0);
                A1 = fmaf(h, cC.z, A1);
            }
            out[e*2+0] = A0;
            out[e*2+1] = A1;
        }
    }
}

extern "C" void kernel_launch(void* const* d_in, const int* in_sizes, int n_in,
                              void* d_out, int out_size, void* d_ws, size_t ws_size,
                              hipStream_t stream) {
    const float* x     = (const float*)d_in[0];
    const float* theta = (const float*)d_in[1];
    const float* W1    = (const float*)d_in[2];
    const float* b1    = (const float*)d_in[3];
    const float* W2    = (const float*)d_in[4];
    const float* b2    = (const float*)d_in[5];
    float* out = (float*)d_out;
    float* tab = (float*)d_ws;

    const int B = in_sizes[0] / 3;

    q_precompute<<<1, 64, 0, stream>>>(theta, W1, b1, W2, b2, tab);

    const int blocks = (B + 2047) / 2048;       // 8 elems/thread * 256 thr
    q_main<<<blocks, 256, 0, stream>>>(x, tab, out, B);
}